// Round 6
// baseline (220.238 us; speedup 1.0000x reference)
//
#include <hip/hip_runtime.h>

#define B 32
#define S 3136
#define C 256
#define W 98            // 32-bit words per channel: 98*32 = 3136
#define THRESH 1568     // cnt >= S*0.5 -> percent >= SIMILARITY -> kill
#define TC 8            // channels per k_mask block
#define NCHUNK 112      // spatial chunks for mean partials (28 rows each) -> 3584 blocks = 14/CU exact
#define CROWS 28        // rows per chunk; 7 per thread (r, r+4, ..., r+24)

typedef float fvec4 __attribute__((ext_vector_type(4)));  // native vector for nontemporal builtins

// ---- pass 1: single read of x: NT-copy out=x AND partial channel sums.
// MLP fix vs prev round: 7 loads batched into registers BEFORE any store,
// so ~7 loads/lane stay in flight instead of load->store->load serialization
// (prev VGPR=36 => <=2 outstanding; this needs ~45 VGPR, still 8 waves/SIMD).
__global__ __launch_bounds__(256) void k_mean_copy(const float* __restrict__ x,
                                                   float* __restrict__ out,
                                                   float* __restrict__ partial) {
    const int b = blockIdx.x;         // 0..31
    const int chunk = blockIdx.y;     // 0..111 (28 rows each)
    const int c4 = threadIdx.x & 63;  // float4 group within channel dim
    const int r  = threadIdx.x >> 6;  // 0..3
    const size_t base = ((size_t)b * S + (size_t)chunk * CROWS + r) * C;
    const float4* p  = (const float4*)(x + base) + c4;
    fvec4*       po  = (fvec4*)(out + base) + c4;

    float4 v[7];
#pragma unroll
    for (int k = 0; k < 7; ++k)                      // issue all 7 loads back-to-back
        v[k] = p[(size_t)k * 4 * (C / 4)];
#pragma unroll
    for (int k = 0; k < 7; ++k) {                    // stores drain as loads land
        fvec4 nv; nv.x = v[k].x; nv.y = v[k].y; nv.z = v[k].z; nv.w = v[k].w;
        __builtin_nontemporal_store(nv, po + (size_t)k * 4 * (C / 4));  // out = x
    }
    float4 sum = make_float4(0.f, 0.f, 0.f, 0.f);
#pragma unroll
    for (int k = 0; k < 7; ++k) {                    // VALU overlaps store drain
        sum.x += v[k].x; sum.y += v[k].y; sum.z += v[k].z; sum.w += v[k].w;
    }

    __shared__ float4 sm[256];
    sm[threadIdx.x] = sum;
    __syncthreads();
    if (r == 0) {
        float4 a = sm[c4], b2 = sm[c4 + 64], c_ = sm[c4 + 128], d = sm[c4 + 192];
        float4 t;
        t.x = a.x + b2.x + c_.x + d.x;
        t.y = a.y + b2.y + c_.y + d.y;
        t.z = a.z + b2.z + c_.z + d.z;
        t.w = a.w + b2.w + c_.w + d.w;
        ((float4*)(partial + ((size_t)b * NCHUNK + chunk) * C))[c4] = t;
    }
}

// ---- pass 1.5: tiny reduction partial -> mean[b][c] (pre-divided by S) ----
__global__ __launch_bounds__(256) void k_mean_final(const float* __restrict__ partial,
                                                    float* __restrict__ mean) {
    const int b = blockIdx.x;     // 0..31
    const int c = threadIdx.x;    // 0..255
    const float* p = partial + (size_t)b * NCHUNK * C + c;
    float s = 0.f;
#pragma unroll
    for (int k = 0; k < NCHUNK; ++k) s += p[(size_t)k * C];
    mean[(size_t)b * C + c] = s * (1.0f / (float)S);
}

// ---- pass 2: bits only. x is L3-resident from pass 1; writes 3.2 MB ----
__global__ __launch_bounds__(64) void k_bits(const float* __restrict__ x,
                                             const float* __restrict__ mean,
                                             unsigned int* __restrict__ bits) {
    const int b  = blockIdx.x;        // 0..31
    const int w  = blockIdx.y;        // 0..97
    const int c4 = threadIdx.x;       // 0..63

    const float4 m = ((const float4*)(mean + (size_t)b * C))[c4];

    const size_t rowbase = ((size_t)b * S + (size_t)w * 32) * C;
    const float4* p = (const float4*)(x + rowbase) + c4;
    unsigned int w0 = 0, w1 = 0, w2 = 0, w3 = 0;
#pragma unroll
    for (int k = 0; k < 32; ++k) {
        float4 v = p[(size_t)k * (C / 4)];
        w0 |= (v.x > m.x) ? (1u << k) : 0u;
        w1 |= (v.y > m.y) ? (1u << k) : 0u;
        w2 |= (v.z > m.z) ? (1u << k) : 0u;
        w3 |= (v.w > m.w) ? (1u << k) : 0u;
    }
    uint4 ob; ob.x = w0; ob.y = w1; ob.z = w2; ob.w = w3;
    ((uint4*)(bits + ((size_t)b * W + w) * C))[c4] = ob;
}

// ---- pass 3: pairwise co-live via popcount + in-place fixup of out ----
// out already holds x (from pass 1). Common case: all live, no writes.
__global__ __launch_bounds__(256) void k_mask_fix(const unsigned int* __restrict__ bits,
                                                  float* __restrict__ out) {
    const int b  = blockIdx.x;          // 0..31
    const int c0 = blockIdx.y * TC;     // channel group this block decides
    const int j  = threadIdx.x;         // partner channel
    const unsigned int* bb = bits + (size_t)b * (W * C);

    unsigned int cnt[TC];
#pragma unroll
    for (int t = 0; t < TC; ++t) cnt[t] = 0;

#pragma unroll 2
    for (int w = 0; w < W; ++w) {
        const unsigned int bj = bb[(size_t)w * C + j];        // coalesced vload
        const unsigned int* bc = bb + (size_t)w * C + c0;     // uniform -> s_load
#pragma unroll
        for (int t = 0; t < TC; ++t)
            cnt[t] += __popc(bj & bc[t]);
    }

    __shared__ unsigned int km;
    if (j == 0) km = 0u;
    __syncthreads();

    unsigned int kill = 0;
#pragma unroll
    for (int t = 0; t < TC; ++t)
        if ((c0 + t) != j && cnt[t] >= THRESH) kill |= (1u << t);
    if (kill) atomicOr(&km, kill);
    __syncthreads();

    const unsigned int k2 = km;
    if (k2 == 0u) return;               // all 8 channels live -> done (fast path)

    // zero killed channels: thread j covers rows j, j+256, ...
#pragma unroll
    for (int t = 0; t < TC; ++t) {
        if ((k2 >> t) & 1u) {
            float* col = out + (size_t)b * S * C + (c0 + t);
            for (int row = j; row < S; row += 256)
                col[(size_t)row * C] = 0.0f;
        }
    }
}

extern "C" void kernel_launch(void* const* d_in, const int* in_sizes, int n_in,
                              void* d_out, int out_size, void* d_ws, size_t ws_size,
                              hipStream_t stream) {
    const float* x = (const float*)d_in[0];
    float* out = (float*)d_out;

    // workspace layout (no init required — every word fully overwritten
    // before first read, with a kernel boundary between write and read)
    float* partial     = (float*)d_ws;                                      // 3.67 MB
    float* meanv       = partial + (size_t)B * NCHUNK * C;                  // 32 KB
    unsigned int* bits = (unsigned int*)(meanv + (size_t)B * C);            // 3.2 MB

    k_mean_copy <<<dim3(B, NCHUNK), 256, 0, stream>>>(x, out, partial);
    k_mean_final<<<dim3(B),         256, 0, stream>>>(partial, meanv);
    k_bits      <<<dim3(B, W),       64, 0, stream>>>(x, meanv, bits);
    k_mask_fix  <<<dim3(B, C / TC), 256, 0, stream>>>(bits, out);
}

// Round 7
// 212.715 us; speedup vs baseline: 1.0354x; 1.0354x over previous
//
#include <hip/hip_runtime.h>

#define B 32
#define S 3136
#define C 256
#define W 98            // 32-bit words per channel: 98*32 = 3136
#define THRESH 1568     // cnt >= S*0.5 -> percent >= SIMILARITY -> kill
#define TC 8            // channels per k_mask block
#define NCHUNK 56       // spatial chunks for mean partials (56 rows each) -> 1792 blocks = 7/CU exact
#define CROWS 56

// ---- pass 1: per-chunk partial sums, float4, pure HBM read stream ----
__global__ __launch_bounds__(256) void k_mean_part(const float* __restrict__ x,
                                                   float* __restrict__ partial) {
    const int b = blockIdx.x;         // 0..31
    const int chunk = blockIdx.y;     // 0..55 (56 rows each)
    const int c4 = threadIdx.x & 63;  // float4 group within channel dim
    const int r  = threadIdx.x >> 6;  // 0..3
    const float4* p = (const float4*)(x + ((size_t)b * S + (size_t)chunk * CROWS + r) * C) + c4;
    float4 sum = make_float4(0.f, 0.f, 0.f, 0.f);
#pragma unroll
    for (int k = 0; k < CROWS / 4; ++k) {   // rows r, r+4, ..., r+52 (14 iters)
        float4 v = p[(size_t)k * 4 * (C / 4)];
        sum.x += v.x; sum.y += v.y; sum.z += v.z; sum.w += v.w;
    }
    __shared__ float4 sm[256];
    sm[threadIdx.x] = sum;
    __syncthreads();
    if (r == 0) {
        float4 a = sm[c4], b2 = sm[c4 + 64], c_ = sm[c4 + 128], d = sm[c4 + 192];
        float4 t;
        t.x = a.x + b2.x + c_.x + d.x;
        t.y = a.y + b2.y + c_.y + d.y;
        t.z = a.z + b2.z + c_.z + d.z;
        t.w = a.w + b2.w + c_.w + d.w;
        ((float4*)(partial + ((size_t)b * NCHUNK + chunk) * C))[c4] = t;
    }
}

// ---- pass 1.5: tiny reduction partial -> mean[b][c] (pre-divided by S) ----
__global__ __launch_bounds__(256) void k_mean_final(const float* __restrict__ partial,
                                                    float* __restrict__ mean) {
    const int b = blockIdx.x;     // 0..31
    const int c = threadIdx.x;    // 0..255
    const float* p = partial + (size_t)b * NCHUNK * C + c;
    float s = 0.f;
#pragma unroll
    for (int k = 0; k < NCHUNK; ++k) s += p[(size_t)k * C];
    mean[(size_t)b * C + c] = s * (1.0f / (float)S);
}

// ---- pass 2: bits + out = x copy. x reads are L3-warm from pass 1;
// PLAIN stores (the NT stores measured 2.45 TB/s vs 6.8 TB/s for plain
// write-only fills — NT was the prime suspect, this is the A/B) ----
__global__ __launch_bounds__(64) void k_bits_copy(const float* __restrict__ x,
                                                  const float* __restrict__ mean,
                                                  unsigned int* __restrict__ bits,
                                                  float* __restrict__ out) {
    const int b  = blockIdx.x;        // 0..31
    const int w  = blockIdx.y;        // 0..97
    const int c4 = threadIdx.x;       // 0..63

    const float4 m = ((const float4*)(mean + (size_t)b * C))[c4];

    const size_t rowbase = ((size_t)b * S + (size_t)w * 32) * C;
    const float4* p  = (const float4*)(x + rowbase) + c4;
    float4*       po = (float4*)(out + rowbase) + c4;
    unsigned int w0 = 0, w1 = 0, w2 = 0, w3 = 0;
#pragma unroll
    for (int k = 0; k < 32; ++k) {
        float4 v = p[(size_t)k * (C / 4)];
        po[(size_t)k * (C / 4)] = v;                    // out = x (plain store)
        w0 |= (v.x > m.x) ? (1u << k) : 0u;
        w1 |= (v.y > m.y) ? (1u << k) : 0u;
        w2 |= (v.z > m.z) ? (1u << k) : 0u;
        w3 |= (v.w > m.w) ? (1u << k) : 0u;
    }
    uint4 ob; ob.x = w0; ob.y = w1; ob.z = w2; ob.w = w3;
    ((uint4*)(bits + ((size_t)b * W + w) * C))[c4] = ob;
}

// ---- pass 3: pairwise co-live via popcount + in-place fixup of out ----
// out already holds x. Common case: all live, no writes.
__global__ __launch_bounds__(256) void k_mask_fix(const unsigned int* __restrict__ bits,
                                                  float* __restrict__ out) {
    const int b  = blockIdx.x;          // 0..31
    const int c0 = blockIdx.y * TC;     // channel group this block decides
    const int j  = threadIdx.x;         // partner channel
    const unsigned int* bb = bits + (size_t)b * (W * C);

    unsigned int cnt[TC];
#pragma unroll
    for (int t = 0; t < TC; ++t) cnt[t] = 0;

#pragma unroll 2
    for (int w = 0; w < W; ++w) {
        const unsigned int bj = bb[(size_t)w * C + j];        // coalesced vload
        const unsigned int* bc = bb + (size_t)w * C + c0;     // uniform -> s_load
#pragma unroll
        for (int t = 0; t < TC; ++t)
            cnt[t] += __popc(bj & bc[t]);
    }

    __shared__ unsigned int km;
    if (j == 0) km = 0u;
    __syncthreads();

    unsigned int kill = 0;
#pragma unroll
    for (int t = 0; t < TC; ++t)
        if ((c0 + t) != j && cnt[t] >= THRESH) kill |= (1u << t);
    if (kill) atomicOr(&km, kill);
    __syncthreads();

    const unsigned int k2 = km;
    if (k2 == 0u) return;               // all 8 channels live -> done (fast path)

    // zero killed channels: thread j covers rows j, j+256, ...
#pragma unroll
    for (int t = 0; t < TC; ++t) {
        if ((k2 >> t) & 1u) {
            float* col = out + (size_t)b * S * C + (c0 + t);
            for (int row = j; row < S; row += 256)
                col[(size_t)row * C] = 0.0f;
        }
    }
}

extern "C" void kernel_launch(void* const* d_in, const int* in_sizes, int n_in,
                              void* d_out, int out_size, void* d_ws, size_t ws_size,
                              hipStream_t stream) {
    const float* x = (const float*)d_in[0];
    float* out = (float*)d_out;

    // workspace layout (no init required — every word fully overwritten
    // before first read, with a kernel boundary between write and read)
    float* partial     = (float*)d_ws;                                      // 1.83 MB
    float* meanv       = partial + (size_t)B * NCHUNK * C;                  // 32 KB
    unsigned int* bits = (unsigned int*)(meanv + (size_t)B * C);            // 3.2 MB

    k_mean_part <<<dim3(B, NCHUNK), 256, 0, stream>>>(x, partial);
    k_mean_final<<<dim3(B),         256, 0, stream>>>(partial, meanv);
    k_bits_copy <<<dim3(B, W),       64, 0, stream>>>(x, meanv, bits, out);
    k_mask_fix  <<<dim3(B, C / TC), 256, 0, stream>>>(bits, out);
}